// Round 6
// baseline (83.992 us; speedup 1.0000x reference)
//
#include <hip/hip_runtime.h>
#include <hip/hip_bf16.h>

// FerroelectricBasis (B=1024, I=64, O=64, N=16)
// out[b,o] = sum_{i,n} [ A*sigmoid_eval + W ]
//   A = 2*Ps*coef, W = (bias-Ps)*coef, kk = -log2e*k, E = log2e*k*Ec
//   sigmoid_eval = 1/(1 + exp2(kk*x[b,i] + (br ? E : -E)))
//   br(b,i) = x[b,i] > x[b-1,i]   (row 0 compares vs 0)
//
// 2 kernels:
//   ferro_fused : per-block param transform -> LDS (64 KB, own i-slice only),
//                 then 16 i-chunks x 32 b-chunks, 8 rows/wave, partials -> ws
//   reduce_k    : sum 16 i-chunk partials -> out
//
// Trans-pipe floor ~7 us (67.1M evals x 2 quarter-rate trans ops).

#define LOG2E 1.44269504088896340736f
#define B_DIM 1024
#define I_DIM 64
#define O_DIM 64
#define N_DIM 16

__device__ __forceinline__ float ex2(float x) {
#if __has_builtin(__builtin_amdgcn_exp2f)
  return __builtin_amdgcn_exp2f(x);
#else
  return exp2f(x);
#endif
}

// grid 512 = ic(16) + bc(32)*16; block 256 = 4 waves; lane = o.
// LDS Qs[(il*16+n)*64+o] = {kk, E, A, W}; 64 KB -> 2 blocks/CU, grid co-resident.
__global__ __launch_bounds__(256) void ferro_fused(
    const float* __restrict__ x, const float* __restrict__ k,
    const float* __restrict__ Ec, const float* __restrict__ Ps,
    const float* __restrict__ bias, const float* __restrict__ coef,
    float* __restrict__ part) {
  __shared__ float4 Qs[4 * N_DIM * O_DIM];   // 64 KB

  int t  = threadIdx.x;
  int o  = t & 63;
  int w  = t >> 6;
  int ic = blockIdx.x & 15;        // same-ic blocks share XCD (blk%8 = ic%8)
  int bc = blockIdx.x >> 4;        // 0..31

  // ---- prep phase: transform this block's i-slice of params into LDS ----
  #pragma unroll
  for (int j = 0; j < 16; ++j) {
    int e   = t + j * 256;         // 0..4095
    int il  = e >> 10;             // local i
    int rem = e & 1023;            // o*16 + n
    int oo  = rem >> 4, n = rem & 15;
    int g   = (ic * 4 + il) * 1024 + rem;   // raw idx = i*1024 + o*16 + n
    float kv = k[g], ev = Ec[g], pv = Ps[g], bv = bias[g], cv = coef[g];
    float kk = -LOG2E * kv;
    float E  =  LOG2E * kv * ev;
    float A  =  2.0f * pv * cv;
    float W  = (bv - pv) * cv;
    Qs[(il * N_DIM + n) * O_DIM + oo] = make_float4(kk, E, A, W);
  }
  __syncthreads();

  // ---- main phase ----
  int r0 = bc * 32 + w * 8;

  float acc[8];
  #pragma unroll
  for (int j = 0; j < 8; ++j) acc[j] = 0.0f;
  float wsum = 0.0f;

  #pragma unroll 1
  for (int il = 0; il < 4; ++il) {
    int i = ic * 4 + il;
    float xv[9];
    xv[0] = (r0 == 0) ? 0.0f : x[(r0 - 1) * I_DIM + i];   // wave-uniform broadcast
    #pragma unroll
    for (int j = 0; j < 8; ++j) xv[j + 1] = x[(r0 + j) * I_DIM + i];
    bool br[8];
    #pragma unroll
    for (int j = 0; j < 8; ++j) br[j] = xv[j + 1] > xv[j];

    const float4* q = &Qs[(il * N_DIM) * O_DIM + o];
    #pragma unroll
    for (int n = 0; n < N_DIM; ++n) {
      float4 p = q[n * O_DIM];                 // ds_read_b128, conflict-free
      float E = p.y, nE = -p.y;
      wsum += p.w;
      #pragma unroll
      for (int j = 0; j < 8; ++j) {
        float e = br[j] ? E : nE;
        float z = fmaf(p.x, xv[j + 1], e);
        float s = __builtin_amdgcn_rcpf(1.0f + ex2(z));
        acc[j] = fmaf(p.z, s, acc[j]);
      }
    }
  }

  float* dst = part + ((size_t)ic * B_DIM + r0) * O_DIM + o;
  #pragma unroll
  for (int j = 0; j < 8; ++j)
    dst[j * O_DIM] = acc[j] + wsum;
}

__global__ __launch_bounds__(256) void reduce_k(
    const float* __restrict__ part, float* __restrict__ out) {
  int gid = blockIdx.x * 256 + threadIdx.x;    // b*64 + o
  float s = 0.f;
  #pragma unroll
  for (int ic = 0; ic < 16; ++ic) s += part[ic * (B_DIM * O_DIM) + gid];
  out[gid] = s;
}

extern "C" void kernel_launch(void* const* d_in, const int* in_sizes, int n_in,
                              void* d_out, int out_size, void* d_ws, size_t ws_size,
                              hipStream_t stream) {
  const float* x    = (const float*)d_in[0];
  const float* k    = (const float*)d_in[1];
  const float* Ec   = (const float*)d_in[2];
  const float* Ps   = (const float*)d_in[3];
  const float* bias = (const float*)d_in[4];
  const float* coef = (const float*)d_in[5];
  float* out = (float*)d_out;

  float* part = (float*)d_ws;                  // 16 * 1024 * 64 * 4B = 4 MB

  hipLaunchKernelGGL(ferro_fused, dim3(512), dim3(256), 0, stream,
                     x, k, Ec, Ps, bias, coef, part);
  hipLaunchKernelGGL(reduce_k, dim3(B_DIM * O_DIM / 256), dim3(256), 0, stream,
                     part, out);
}

// Round 9
// 83.053 us; speedup vs baseline: 1.0113x; 1.0113x over previous
//
#include <hip/hip_runtime.h>
#include <hip/hip_bf16.h>

// FerroelectricBasis (B=1024, I=64, O=64, N=16)
// out[b,o] = sum_{i,n} [ A*sigmoid_eval + W ]
//   A = 2*Ps*coef, W = (bias-Ps)*coef, kk = -log2e*k, E = log2e*k*Ec
//   sigmoid_eval = 1/(1 + exp2(kk*x[b,i] + (br ? E : -E)))
//   br(b,i) = x[b,i] > x[b-1,i]   (row 0 compares vs 0)
//
// R7-R9: pairwise-denominator (exact): A0/u0 + A1/u1 = (A0*u1 + A1*u0)/(u0*u1),
//     u = 1 + 2^z. Halves v_rcp count: per 2 evals 4 trans -> 3 trans.
//     Discriminates trans-bound (expect -4..-9 us) vs harness-floor (null).
//     (4-way rejected: den would reach ~2^108 -> f32 overflow; 2-way <= ~2^54.)
//
// 2 kernels:
//   ferro_fused : per-block param transform -> LDS (64 KB, own i-slice only),
//                 16 i-chunks x 32 b-chunks, 8 rows/wave, partials -> ws
//   reduce_k    : sum 16 i-chunk partials -> out

#define LOG2E 1.44269504088896340736f
#define B_DIM 1024
#define I_DIM 64
#define O_DIM 64
#define N_DIM 16

__device__ __forceinline__ float ex2(float x) {
#if __has_builtin(__builtin_amdgcn_exp2f)
  return __builtin_amdgcn_exp2f(x);
#else
  return exp2f(x);
#endif
}

// grid 512 = ic(16) + bc(32)*16; block 256 = 4 waves; lane = o.
// LDS Qs[(il*16+n)*64+o] = {kk, E, A, W}; 64 KB -> 2 blocks/CU, grid co-resident.
__global__ __launch_bounds__(256) void ferro_fused(
    const float* __restrict__ x, const float* __restrict__ k,
    const float* __restrict__ Ec, const float* __restrict__ Ps,
    const float* __restrict__ bias, const float* __restrict__ coef,
    float* __restrict__ part) {
  __shared__ float4 Qs[4 * N_DIM * O_DIM];   // 64 KB

  int t  = threadIdx.x;
  int o  = t & 63;
  int w  = t >> 6;
  int ic = blockIdx.x & 15;        // same-ic blocks share XCD (blk%8 = ic%8)
  int bc = blockIdx.x >> 4;        // 0..31

  // ---- prep phase: transform this block's i-slice of params into LDS ----
  #pragma unroll
  for (int j = 0; j < 16; ++j) {
    int e   = t + j * 256;         // 0..4095
    int il  = e >> 10;             // local i
    int rem = e & 1023;            // o*16 + n
    int oo  = rem >> 4, n = rem & 15;
    int g   = (ic * 4 + il) * 1024 + rem;   // raw idx = i*1024 + o*16 + n
    float kv = k[g], ev = Ec[g], pv = Ps[g], bv = bias[g], cv = coef[g];
    float kk = -LOG2E * kv;
    float E  =  LOG2E * kv * ev;
    float A  =  2.0f * pv * cv;
    float W  = (bv - pv) * cv;
    Qs[(il * N_DIM + n) * O_DIM + oo] = make_float4(kk, E, A, W);
  }
  __syncthreads();

  // ---- main phase ----
  int r0 = bc * 32 + w * 8;

  float acc[8];
  #pragma unroll
  for (int j = 0; j < 8; ++j) acc[j] = 0.0f;
  float wsum = 0.0f;

  #pragma unroll 1
  for (int il = 0; il < 4; ++il) {
    int i = ic * 4 + il;
    float xv[9];
    xv[0] = (r0 == 0) ? 0.0f : x[(r0 - 1) * I_DIM + i];   // wave-uniform broadcast
    #pragma unroll
    for (int j = 0; j < 8; ++j) xv[j + 1] = x[(r0 + j) * I_DIM + i];
    bool br[8];
    #pragma unroll
    for (int j = 0; j < 8; ++j) br[j] = xv[j + 1] > xv[j];

    const float4* q = &Qs[(il * N_DIM) * O_DIM + o];
    #pragma unroll
    for (int np = 0; np < N_DIM / 2; ++np) {
      float4 p0 = q[(2 * np + 0) * O_DIM];   // ds_read_b128, conflict-free
      float4 p1 = q[(2 * np + 1) * O_DIM];
      wsum += p0.w + p1.w;
      float E0 = p0.y, E1 = p1.y;
      #pragma unroll
      for (int j = 0; j < 8; ++j) {
        float e0 = br[j] ? E0 : -E0;
        float e1 = br[j] ? E1 : -E1;
        float t0 = ex2(fmaf(p0.x, xv[j + 1], e0));
        float t1 = ex2(fmaf(p1.x, xv[j + 1], e1));
        float u0 = t0 + 1.0f;
        float u1 = t1 + 1.0f;
        float den = u0 * u1;                       // (1+t0)(1+t1), <= ~2^54
        float num = fmaf(p0.z, u1, p1.z * u0);     // A0*u1 + A1*u0
        float r   = __builtin_amdgcn_rcpf(den);    // one rcp per pair
        acc[j] = fmaf(num, r, acc[j]);
      }
    }
  }

  float* dst = part + ((size_t)ic * B_DIM + r0) * O_DIM + o;
  #pragma unroll
  for (int j = 0; j < 8; ++j)
    dst[j * O_DIM] = acc[j] + wsum;
}

__global__ __launch_bounds__(256) void reduce_k(
    const float* __restrict__ part, float* __restrict__ out) {
  int gid = blockIdx.x * 256 + threadIdx.x;    // b*64 + o
  float s = 0.f;
  #pragma unroll
  for (int ic = 0; ic < 16; ++ic) s += part[ic * (B_DIM * O_DIM) + gid];
  out[gid] = s;
}

extern "C" void kernel_launch(void* const* d_in, const int* in_sizes, int n_in,
                              void* d_out, int out_size, void* d_ws, size_t ws_size,
                              hipStream_t stream) {
  const float* x    = (const float*)d_in[0];
  const float* k    = (const float*)d_in[1];
  const float* Ec   = (const float*)d_in[2];
  const float* Ps   = (const float*)d_in[3];
  const float* bias = (const float*)d_in[4];
  const float* coef = (const float*)d_in[5];
  float* out = (float*)d_out;

  float* part = (float*)d_ws;                  // 16 * 1024 * 64 * 4B = 4 MB

  hipLaunchKernelGGL(ferro_fused, dim3(512), dim3(256), 0, stream,
                     x, k, Ec, Ps, bias, coef, part);
  hipLaunchKernelGGL(reduce_k, dim3(B_DIM * O_DIM / 256), dim3(256), 0, stream,
                     part, out);
}